// Round 5
// baseline (697.515 us; speedup 1.0000x reference)
//
#include <hip/hip_runtime.h>
#include <hip/hip_bf16.h>
#include <stdint.h>

// Problem constants (FujiSparseMoE): S=2048 B=2 D=1024 E=64 K=2 I=512 SI=512 CAP=256
#define T_TOK 4096
#define DDIM  1024
#define NEXP  64
#define IDIM  512
#define SIDIM 512
#define CAP   256
#define KZ    8     // logits K-split

typedef __attribute__((ext_vector_type(4))) float f32x4;
typedef __attribute__((ext_vector_type(8))) short bf16x8;   // 8 bf16 raw (4 VGPRs)

// 8 fp32 -> 8 bf16 (RNE) via packed converts
__device__ __forceinline__ bf16x8 cvt8(f32x4 a, f32x4 b) {
    union { __hip_bfloat162 h[4]; bf16x8 v; } u;
    u.h[0] = __float22bfloat162_rn(make_float2(a[0], a[1]));
    u.h[1] = __float22bfloat162_rn(make_float2(a[2], a[3]));
    u.h[2] = __float22bfloat162_rn(make_float2(b[0], b[1]));
    u.h[3] = __float22bfloat162_rn(make_float2(b[2], b[3]));
    return u.v;
}
__device__ __forceinline__ short f2bs(float f) {
    union { __hip_bfloat16 h; short s; } u; u.h = __float2bfloat16(f); return u.s;
}

// async global->LDS, 16B per lane; LDS dest is wave-uniform base + lane*16
__device__ __forceinline__ void gload16(const void* g, void* l) {
    __builtin_amdgcn_global_load_lds((const __attribute__((address_space(1))) void*)g,
                                     (__attribute__((address_space(3))) void*)l, 16, 0, 0);
}

// bf16 LDS tile: 64-B rows (4 x 16-B slots), slot swizzle sw(row) = (row>>1)&3.
// 16 lanes reading rows R0+fm at fixed sk hit each bank-group exactly 2x (2-way = free).
__device__ __forceinline__ bf16x8 fragbf(const char* base, int row, int sk) {
    return *(const bf16x8*)(base + row * 64 + ((sk ^ ((row >> 1) & 3)) << 4));
}

// ---------------- weight convert fp32 -> bf16 (RNE; identical to GEMM-side cvt)
__global__ __launch_bounds__(256) void cvtw(const float* __restrict__ src,
                                            short* __restrict__ dst, int n8) {
    int i = blockIdx.x * blockDim.x + threadIdx.x;
    int stride = gridDim.x * blockDim.x;
    for (; i < n8; i += stride) {
        f32x4 lo = *(const f32x4*)(src + (size_t)i * 8);
        f32x4 hi = *(const f32x4*)(src + (size_t)i * 8 + 4);
        *(bf16x8*)(dst + (size_t)i * 8) = cvt8(lo, hi);
    }
}

// ---------------- logits partials (fp32 exact): lpart[kz][T,E], kz splits K in 8
__global__ __launch_bounds__(256) void logits_kernel(const float* __restrict__ X,
                                                     const float* __restrict__ RW,
                                                     float* __restrict__ lpart) {
    __shared__ float sX[64 * 33];
    __shared__ float sW[64 * 33];
    int m0 = blockIdx.x * 64;
    int kz = blockIdx.y;               // 0..7
    int kbase = kz * (DDIM / KZ);      // 128 K each
    int tid = threadIdx.x;
    int tg = tid >> 4;                 // 16 groups -> rows tg*4..+4
    int eg = tid & 15;                 // experts eg*4..+4
    float acc[4][4] = {};
    for (int k0 = 0; k0 < DDIM / KZ; k0 += 32) {
        __syncthreads();
#pragma unroll
        for (int i = 0; i < 8; ++i) {
            int idx = i * 256 + tid;   // 0..2047
            int r = idx >> 5, c = idx & 31;
            sX[r * 33 + c] = X[(size_t)(m0 + r) * DDIM + kbase + k0 + c];
            sW[r * 33 + c] = RW[(size_t)r * DDIM + kbase + k0 + c];
        }
        __syncthreads();
#pragma unroll 4
        for (int k = 0; k < 32; ++k) {
            float xv[4], wv[4];
#pragma unroll
            for (int i = 0; i < 4; ++i) xv[i] = sX[(tg * 4 + i) * 33 + k];
#pragma unroll
            for (int j = 0; j < 4; ++j) wv[j] = sW[(eg * 4 + j) * 33 + k];
#pragma unroll
            for (int i = 0; i < 4; ++i)
#pragma unroll
                for (int j = 0; j < 4; ++j) acc[i][j] += xv[i] * wv[j];
        }
    }
    float* outp = lpart + (size_t)kz * T_TOK * NEXP;
#pragma unroll
    for (int i = 0; i < 4; ++i)
#pragma unroll
        for (int j = 0; j < 4; ++j)
            outp[(size_t)(m0 + tg * 4 + i) * NEXP + eg * 4 + j] = acc[i][j];
}

// ---------------- softmax + top2 + dispatch + probs out (fp32) + shared sigmoid gate
__global__ __launch_bounds__(256) void topk_kernel(const float* __restrict__ lpart,
                                                   const float* __restrict__ X,
                                                   const float* __restrict__ SEG,
                                                   float* __restrict__ probs_out,
                                                   int* __restrict__ counts,
                                                   int* __restrict__ tok_slot,
                                                   float* __restrict__ w_slot,
                                                   float* __restrict__ gate_sh) {
    int lane = threadIdx.x & 63;
    int wv   = threadIdx.x >> 6;
    int t    = blockIdx.x * 4 + wv;            // one wave per token, lane = expert
    size_t li = (size_t)t * NEXP + lane;
    float l = 0.f;
#pragma unroll
    for (int z = 0; z < KZ; ++z) l += lpart[(size_t)z * T_TOK * NEXP + li];
    float mx = l;
    for (int s = 32; s; s >>= 1) mx = fmaxf(mx, __shfl_xor(mx, s));
    float e = __expf(l - mx);
    float sum = e;
    for (int s = 32; s; s >>= 1) sum += __shfl_xor(sum, s);
    float prob = e / sum;
    probs_out[li] = prob;
    float v = prob; int idx = lane;
    for (int s = 32; s; s >>= 1) {
        float ov = __shfl_xor(v, s); int oi = __shfl_xor(idx, s);
        if (ov > v || (ov == v && oi < idx)) { v = ov; idx = oi; }
    }
    float v1 = v; int i1 = idx;
    v = (lane == i1) ? -1e30f : prob; idx = lane;
    for (int s = 32; s; s >>= 1) {
        float ov = __shfl_xor(v, s); int oi = __shfl_xor(idx, s);
        if (ov > v || (ov == v && oi < idx)) { v = ov; idx = oi; }
    }
    float v2 = v; int i2 = idx;
    float denom = v1 + v2 + 1e-9f;
    if (lane == 0) {
        int s1 = atomicAdd(&counts[i1], 1);
        if (s1 < CAP) { tok_slot[i1 * CAP + s1] = t; w_slot[i1 * CAP + s1] = v1 / denom; }
        int s2 = atomicAdd(&counts[i2], 1);
        if (s2 < CAP) { tok_slot[i2 * CAP + s2] = t; w_slot[i2 * CAP + s2] = v2 / denom; }
    }
    float g = 0.f;
    const float* xr = X + (size_t)t * DDIM + lane * 16;
    const float* sr = SEG + lane * 16;
#pragma unroll
    for (int j = 0; j < 4; ++j) {
        f32x4 xv = *(const f32x4*)(xr + j * 4);
        f32x4 sv = *(const f32x4*)(sr + j * 4);
#pragma unroll
        for (int q = 0; q < 4; ++q) g += xv[q] * sv[q];
    }
    for (int s = 32; s; s >>= 1) g += __shfl_xor(g, s);
    if (lane == 0) gate_sh[t] = 1.f / (1.f + __expf(-g));
}

// ---------------- gather X -> xg (bf16, per expert slot) and X -> xsh (bf16)
__global__ __launch_bounds__(256) void xgather(const float* __restrict__ X,
                                               const int* __restrict__ counts,
                                               const int* __restrict__ tok_slot,
                                               short* __restrict__ xg,
                                               short* __restrict__ xsh) {
    int b = blockIdx.x, tid = threadIdx.x;
    if (b < 512) {
        int r = b & 7, j = b >> 3;
        int e = (j & 7) * 8 + r;                // e%8 == b%8 -> writer XCD matches gateup reader
        int s0 = (j >> 3) * 32;                 // 32 slots per block
        int M = counts[e]; if (M > CAP) M = CAP;
        for (int i = tid; i < 32 * 128; i += 256) {
            int sl = s0 + (i >> 7);
            int ch = i & 127;
            int src = (sl < M) ? tok_slot[e * CAP + sl] : 0;
            const float* p = X + (size_t)src * DDIM + ch * 8;
            f32x4 lo = *(const f32x4*)p, hi = *(const f32x4*)(p + 4);
            *(bf16x8*)(xg + ((size_t)e * CAP + sl) * DDIM + ch * 8) = cvt8(lo, hi);
        }
    } else {
        int r0 = (b - 512) * 32;
        for (int i = tid; i < 32 * 128; i += 256) {
            int row = r0 + (i >> 7), ch = i & 127;
            const float* p = X + (size_t)row * DDIM + ch * 8;
            f32x4 lo = *(const f32x4*)p, hi = *(const f32x4*)(p + 4);
            *(bf16x8*)(xsh + (size_t)row * DDIM + ch * 8) = cvt8(lo, hi);
        }
    }
}

// ---------------- fused gate/up GEMM + SwiGLU -> act (bf16), all-bf16 operands
// 1-D grid 1280: f<1024 expert (XCD-pinned: e%8 == f%8), f>=1024 shared.
// BM=128, BN=64 (g and u each), BK=32, 4 waves (2x2), wave tile 64x32.
// Stage = A 8K + Bg 4K + Bu 4K = 16K; x2 buffers = 32K LDS -> 4-5 blocks/CU.
__global__ __launch_bounds__(256, 4) void gateup_all(const short* __restrict__ xg,
                                                     const short* __restrict__ xsh,
                                                     const short* __restrict__ gupb,
                                                     const short* __restrict__ sgb,
                                                     const short* __restrict__ subw,
                                                     const int* __restrict__ counts,
                                                     short* __restrict__ act,
                                                     short* __restrict__ act_sh) {
    __shared__ char smem[2 * 16384];
    const int NS = DDIM / 32;          // 32 stages
    int f = blockIdx.x;
    bool expert = f < 1024;
    int e = 0, m0, n0, M;
    const short *Wgb, *Wub, *Abase;
    short* act_out;
    size_t out_base, arow0;
    if (expert) {
        int r = f & 7, q = (f >> 3) & 7, n = (f >> 6) & 7, y = f >> 9;
        e = q * 8 + r;
        n0 = n * 64; m0 = y * 128;
        M = counts[e]; if (M > CAP) M = CAP;
        if (m0 >= M) return;
        Wgb = gupb + (size_t)e * (2 * IDIM) * DDIM;
        Wub = Wgb + (size_t)IDIM * DDIM;
        Abase = xg; arow0 = (size_t)e * CAP + m0;
        act_out = act; out_base = (size_t)e * CAP * IDIM;
    } else {
        int g = f - 1024;
        int mp = g & 31, n = g >> 5;
        n0 = n * 64; m0 = mp * 128;
        M = T_TOK; Wgb = sgb; Wub = subw;
        Abase = xsh; arow0 = (size_t)m0;
        act_out = act_sh; out_base = 0;
    }
    int tid = threadIdx.x, lane = tid & 63, wv = tid >> 6;
    int wm = wv >> 1, wn = wv & 1;

    // staging: 16 chunks of 1KB/stage; wave wv does {wv, wv+4 (A rows +-64), wv+8 (Bg), wv+12 (Bu)}
    int gsl = (lane & 3) ^ ((lane >> 3) & 3);       // inverse of read swizzle
    int crow = wv * 16 + (lane >> 2);               // chunk-local row
    const short* gpA0 = Abase + (arow0 + crow) * DDIM + gsl * 8;
    const short* gpA1 = Abase + (arow0 + crow + 64) * DDIM + gsl * 8;
    const short* gpBg = Wgb + (size_t)(n0 + crow) * DDIM + gsl * 8;
    const short* gpBu = Wub + (size_t)(n0 + crow) * DDIM + gsl * 8;
    int oA0 = wv * 1024, oA1 = (wv + 4) * 1024;
    int oBg = 8192 + wv * 1024, oBu = 12288 + wv * 1024;

    auto issue = [&](int buf, int s) {
        char* base = smem + buf * 16384;
        int k = s * 32;
        gload16(gpA0 + k, base + oA0);
        gload16(gpA1 + k, base + oA1);
        gload16(gpBg + k, base + oBg);
        gload16(gpBu + k, base + oBu);
    };

    int fm = lane & 15, sk = lane >> 4;
    f32x4 accg[4][2] = {}, accu[4][2] = {};
    auto compute = [&](int buf) {
        const char* base = smem + buf * 16384;
        bf16x8 bg[2], bu[2];
#pragma unroll
        for (int nt = 0; nt < 2; ++nt) {
            int row = wn * 32 + nt * 16 + fm;
            bg[nt] = fragbf(base + 8192, row, sk);
            bu[nt] = fragbf(base + 12288, row, sk);
        }
#pragma unroll
        for (int mt = 0; mt < 4; ++mt) {
            bf16x8 a = fragbf(base, wm * 64 + mt * 16 + fm, sk);
#pragma unroll
            for (int nt = 0; nt < 2; ++nt) {
                accg[mt][nt] = __builtin_amdgcn_mfma_f32_16x16x32_bf16(a, bg[nt], accg[mt][nt], 0, 0, 0);
                accu[mt][nt] = __builtin_amdgcn_mfma_f32_16x16x32_bf16(a, bu[nt], accu[mt][nt], 0, 0, 0);
            }
        }
    };

    issue(0, 0);
#pragma unroll 1
    for (int s = 0; s < NS; s += 2) {
        __syncthreads();                 // buf0 (stage s) landed
        if (s + 1 < NS) issue(1, s + 1);
        compute(0);
        __syncthreads();                 // buf1 (stage s+1) landed
        if (s + 2 < NS) issue(0, s + 2);
        compute(1);
    }

    int frow = (lane >> 4) * 4, fcol = lane & 15;
#pragma unroll
    for (int mt = 0; mt < 4; ++mt)
#pragma unroll
        for (int r = 0; r < 4; ++r) {
            int row = m0 + wm * 64 + mt * 16 + frow + r;
            if (row < M) {
#pragma unroll
                for (int nt = 0; nt < 2; ++nt) {
                    float g = accg[mt][nt][r];
                    float u = accu[mt][nt][r];
                    float a = (g / (1.f + __expf(-g))) * u;      // silu(g)*u
                    act_out[out_base + (size_t)row * IDIM + (n0 + wn * 32 + nt * 16 + fcol)] = f2bs(a);
                }
            }
        }
}

// ---------------- fused down GEMM (all bf16), expert + shared, atomicAdd into zeroed out
// BM=128, BN=128, BK=32, 4 waves, wave tile 64x64. NS=16.
// Stage = A 8K + B 8K = 16K; x2 = 32K LDS -> 4-5 blocks/CU.
__global__ __launch_bounds__(256, 4) void down_all(const short* __restrict__ act,
                                                   const short* __restrict__ act_sh,
                                                   const short* __restrict__ dwb,
                                                   const short* __restrict__ sdb,
                                                   const int* __restrict__ counts,
                                                   const int* __restrict__ tok_slot,
                                                   const float* __restrict__ w_slot,
                                                   const float* __restrict__ gate_sh,
                                                   float* __restrict__ out) {
    __shared__ char smem[2 * 16384];
    const int KD = IDIM;               // 512 both paths
    const int NS = KD / 32;            // 16 stages
    int f = blockIdx.x;
    bool expert = f < 1024;
    int e = 0, m0, n0, M;
    const short *A, *W;
    if (expert) {
        int r = f & 7, q = (f >> 3) & 7, n = (f >> 6) & 7, y = f >> 9;
        e = q * 8 + r;
        n0 = n * 128; m0 = y * 128;
        M = counts[e]; if (M > CAP) M = CAP;
        if (m0 >= M) return;
        A = act + (size_t)e * CAP * IDIM;
        W = dwb + (size_t)e * DDIM * IDIM;
    } else {
        int g = f - 1024;
        int mp = g & 31, n = g >> 5;
        n0 = n * 128; m0 = mp * 128;
        M = T_TOK; A = act_sh; W = sdb;
    }
    int tid = threadIdx.x, lane = tid & 63, wv = tid >> 6;
    int wm = wv >> 1, wn = wv & 1;

    // staging: 16 chunks; wave wv does {wv, wv+4} A rows / {wv+8, wv+12} B rows (each +-64)
    int gsl = (lane & 3) ^ ((lane >> 3) & 3);
    int crow = wv * 16 + (lane >> 2);
    const short* gpA0 = A + (size_t)(m0 + crow) * KD + gsl * 8;
    const short* gpA1 = A + (size_t)(m0 + crow + 64) * KD + gsl * 8;
    const short* gpB0 = W + (size_t)(n0 + crow) * KD + gsl * 8;
    const short* gpB1 = W + (size_t)(n0 + crow + 64) * KD + gsl * 8;
    int oA0 = wv * 1024, oA1 = (wv + 4) * 1024;
    int oB0 = 8192 + wv * 1024, oB1 = 8192 + (wv + 4) * 1024;

    auto issue = [&](int buf, int s) {
        char* base = smem + buf * 16384;
        int k = s * 32;
        gload16(gpA0 + k, base + oA0);
        gload16(gpA1 + k, base + oA1);
        gload16(gpB0 + k, base + oB0);
        gload16(gpB1 + k, base + oB1);
    };

    int fm = lane & 15, sk = lane >> 4;
    f32x4 acc[4][4] = {};
    auto compute = [&](int buf) {
        const char* base = smem + buf * 16384;
        bf16x8 b[4];
#pragma unroll
        for (int nt = 0; nt < 4; ++nt)
            b[nt] = fragbf(base + 8192, wn * 64 + nt * 16 + fm, sk);
#pragma unroll
        for (int mt = 0; mt < 4; ++mt) {
            bf16x8 a = fragbf(base, wm * 64 + mt * 16 + fm, sk);
#pragma unroll
            for (int nt = 0; nt < 4; ++nt)
                acc[mt][nt] = __builtin_amdgcn_mfma_f32_16x16x32_bf16(a, b[nt], acc[mt][nt], 0, 0, 0);
        }
    };

    issue(0, 0);
#pragma unroll 1
    for (int s = 0; s < NS; s += 2) {
        __syncthreads();
        if (s + 1 < NS) issue(1, s + 1);
        compute(0);
        __syncthreads();
        if (s + 2 < NS) issue(0, s + 2);
        compute(1);
    }

    int frow = (lane >> 4) * 4, fcol = lane & 15;
#pragma unroll
    for (int mt = 0; mt < 4; ++mt)
#pragma unroll
        for (int r = 0; r < 4; ++r) {
            int row = m0 + wm * 64 + mt * 16 + frow + r;
            if (row >= M) continue;
            float scale; int trow;
            if (expert) { scale = w_slot[e * CAP + row]; trow = tok_slot[e * CAP + row]; }
            else        { scale = gate_sh[row];          trow = row; }
#pragma unroll
            for (int nt = 0; nt < 4; ++nt) {
                int col = n0 + wn * 64 + nt * 16 + fcol;
                atomicAdd(&out[(size_t)trow * DDIM + col], acc[mt][nt][r] * scale);
            }
        }
}

extern "C" void kernel_launch(void* const* d_in, const int* in_sizes, int n_in,
                              void* d_out, int out_size, void* d_ws, size_t ws_size,
                              hipStream_t stream) {
    const float* X   = (const float*)d_in[0];   // hidden_states  [T, D] fp32
    const float* RW  = (const float*)d_in[1];   // router_w       [E, D]
    const float* GUP = (const float*)d_in[2];   // gate_up_proj   [E, 2I, D]
    const float* DW  = (const float*)d_in[3];   // down_proj      [E, D, I]
    const float* SG  = (const float*)d_in[4];   // sh_gate_w      [SI, D]
    const float* SU  = (const float*)d_in[5];   // sh_up_w        [SI, D]
    const float* SD  = (const float*)d_in[6];   // sh_down_w      [D, SI]
    const float* SEG = (const float*)d_in[7];   // sh_expert_gate_w [1, D]
    float* out = (float*)d_out;                 // [T*D] out, then [T*E] probs (fp32)

    char* ws = (char*)d_ws;
    size_t off = 0;
    float* lpart    = (float*)(ws + off); off += (size_t)KZ * T_TOK * NEXP * 4;      // 8 MB
    int*   counts   = (int*)  (ws + off); off += 1024;
    int*   tok_slot = (int*)  (ws + off); off += (size_t)NEXP * CAP * 4;             // 64 KB
    float* w_slot   = (float*)(ws + off); off += (size_t)NEXP * CAP * 4;             // 64 KB
    float* gate_sh  = (float*)(ws + off); off += (size_t)T_TOK * 4;                  // 16 KB
    short* act      = (short*)(ws + off); off += (size_t)NEXP * CAP * IDIM * 2;      // 16 MB
    short* act_sh   = (short*)(ws + off); off += (size_t)T_TOK * SIDIM * 2;          // 4 MB
    short* xg       = (short*)(ws + off); off += (size_t)NEXP * CAP * DDIM * 2;      // 32 MB
    short* xsh      = (short*)(ws + off); off += (size_t)T_TOK * DDIM * 2;           // 8 MB
    short* gupb     = (short*)(ws + off); off += (size_t)NEXP * 2 * IDIM * DDIM * 2; // 128 MB
    short* dwb      = (short*)(ws + off); off += (size_t)NEXP * DDIM * IDIM * 2;     // 64 MB
    short* sgb      = (short*)(ws + off); off += (size_t)SIDIM * DDIM * 2;           // 1 MB
    short* subw     = (short*)(ws + off); off += (size_t)SIDIM * DDIM * 2;           // 1 MB
    short* sdb      = (short*)(ws + off); off += (size_t)DDIM * SIDIM * 2;           // 1 MB
    (void)ws_size; (void)in_sizes; (void)n_in; (void)out_size;

    hipMemsetAsync(counts, 0, NEXP * sizeof(int), stream);
    hipMemsetAsync(out, 0, (size_t)T_TOK * DDIM * sizeof(float), stream);  // down_all atomicAdds

    cvtw<<<2048, 256, 0, stream>>>(GUP, gupb, NEXP * 2 * IDIM * DDIM / 8);
    cvtw<<<2048, 256, 0, stream>>>(DW, dwb, NEXP * DDIM * IDIM / 8);
    cvtw<<<256, 256, 0, stream>>>(SG, sgb, SIDIM * DDIM / 8);
    cvtw<<<256, 256, 0, stream>>>(SU, subw, SIDIM * DDIM / 8);
    cvtw<<<256, 256, 0, stream>>>(SD, sdb, DDIM * SIDIM / 8);

    logits_kernel<<<dim3(T_TOK / 64, KZ), 256, 0, stream>>>(X, RW, lpart);
    topk_kernel<<<T_TOK / 4, 256, 0, stream>>>(lpart, X, SEG,
                                               out + (size_t)T_TOK * DDIM,
                                               counts, tok_slot, w_slot, gate_sh);
    xgather<<<640, 256, 0, stream>>>(X, counts, tok_slot, xg, xsh);
    gateup_all<<<1280, 256, 0, stream>>>(xg, xsh, gupb, sgb, subw, counts, act, act_sh);
    down_all<<<1280, 256, 0, stream>>>(act, act_sh, dwb, sdb, counts, tok_slot,
                                       w_slot, gate_sh, out);
}

// Round 6
// 660.137 us; speedup vs baseline: 1.0566x; 1.0566x over previous
//
#include <hip/hip_runtime.h>
#include <hip/hip_bf16.h>
#include <stdint.h>

// Problem constants (FujiSparseMoE): S=2048 B=2 D=1024 E=64 K=2 I=512 SI=512 CAP=256
#define T_TOK 4096
#define DDIM  1024
#define NEXP  64
#define IDIM  512
#define SIDIM 512
#define CAP   256
#define KZ    8     // logits K-split

typedef __attribute__((ext_vector_type(4))) float f32x4;
typedef __attribute__((ext_vector_type(8))) short bf16x8;   // 8 bf16 raw (4 VGPRs)

// 8 fp32 -> 8 bf16 (RNE) via packed converts
__device__ __forceinline__ bf16x8 cvt8(f32x4 a, f32x4 b) {
    union { __hip_bfloat162 h[4]; bf16x8 v; } u;
    u.h[0] = __float22bfloat162_rn(make_float2(a[0], a[1]));
    u.h[1] = __float22bfloat162_rn(make_float2(a[2], a[3]));
    u.h[2] = __float22bfloat162_rn(make_float2(b[0], b[1]));
    u.h[3] = __float22bfloat162_rn(make_float2(b[2], b[3]));
    return u.v;
}
__device__ __forceinline__ short f2bs(float f) {
    union { __hip_bfloat16 h; short s; } u; u.h = __float2bfloat16(f); return u.s;
}

// async global->LDS, 16B per lane; LDS dest is wave-uniform base + lane*16 (global src per-lane)
__device__ __forceinline__ void gload16(const void* g, void* l) {
    __builtin_amdgcn_global_load_lds((const __attribute__((address_space(1))) void*)g,
                                     (__attribute__((address_space(3))) void*)l, 16, 0, 0);
}

// fp32 LDS tile: 128-B rows (8 x 16-B slots), source pre-swizzled slot^(row&7).
// Returns bf16 fragment for k = s*8 .. s*8+7 of the given row. (R4-verified)
__device__ __forceinline__ bf16x8 frag32(const char* reg0, int row, int s) {
    const char* p = reg0 + row * 128;
    int sw = row & 7;
    f32x4 lo = *(const f32x4*)(p + (((2 * s) ^ sw) << 4));
    f32x4 hi = *(const f32x4*)(p + (((2 * s + 1) ^ sw) << 4));
    return cvt8(lo, hi);
}
// bf16 LDS tile: 64-B rows (4 x 16-B slots), slot swizzle sk^((row>>1)&3). (R5-verified)
__device__ __forceinline__ bf16x8 fragbf(const char* base, int row, int sk) {
    return *(const bf16x8*)(base + row * 64 + ((sk ^ ((row >> 1) & 3)) << 4));
}

// ---------------- logits partials (fp32 exact): lpart[kz][T,E]
__global__ __launch_bounds__(256) void logits_kernel(const float* __restrict__ X,
                                                     const float* __restrict__ RW,
                                                     float* __restrict__ lpart) {
    __shared__ float sX[64 * 33];
    __shared__ float sW[64 * 33];
    int m0 = blockIdx.x * 64;
    int kz = blockIdx.y;               // 0..7
    int kbase = kz * (DDIM / KZ);      // 128 K each
    int tid = threadIdx.x;
    int tg = tid >> 4;
    int eg = tid & 15;
    float acc[4][4] = {};
    for (int k0 = 0; k0 < DDIM / KZ; k0 += 32) {
        __syncthreads();
#pragma unroll
        for (int i = 0; i < 8; ++i) {
            int idx = i * 256 + tid;
            int r = idx >> 5, c = idx & 31;
            sX[r * 33 + c] = X[(size_t)(m0 + r) * DDIM + kbase + k0 + c];
            sW[r * 33 + c] = RW[(size_t)r * DDIM + kbase + k0 + c];
        }
        __syncthreads();
#pragma unroll 4
        for (int k = 0; k < 32; ++k) {
            float xv[4], wv[4];
#pragma unroll
            for (int i = 0; i < 4; ++i) xv[i] = sX[(tg * 4 + i) * 33 + k];
#pragma unroll
            for (int j = 0; j < 4; ++j) wv[j] = sW[(eg * 4 + j) * 33 + k];
#pragma unroll
            for (int i = 0; i < 4; ++i)
#pragma unroll
                for (int j = 0; j < 4; ++j) acc[i][j] += xv[i] * wv[j];
        }
    }
    float* outp = lpart + (size_t)kz * T_TOK * NEXP;
#pragma unroll
    for (int i = 0; i < 4; ++i)
#pragma unroll
        for (int j = 0; j < 4; ++j)
            outp[(size_t)(m0 + tg * 4 + i) * NEXP + eg * 4 + j] = acc[i][j];
}

// ---------------- softmax + top2 + dispatch + probs out + shared sigmoid gate
__global__ __launch_bounds__(256) void topk_kernel(const float* __restrict__ lpart,
                                                   const float* __restrict__ X,
                                                   const float* __restrict__ SEG,
                                                   float* __restrict__ probs_out,
                                                   int* __restrict__ counts,
                                                   int* __restrict__ tok_slot,
                                                   float* __restrict__ w_slot,
                                                   float* __restrict__ gate_sh) {
    int lane = threadIdx.x & 63;
    int wv   = threadIdx.x >> 6;
    int t    = blockIdx.x * 4 + wv;
    size_t li = (size_t)t * NEXP + lane;
    float l = 0.f;
#pragma unroll
    for (int z = 0; z < KZ; ++z) l += lpart[(size_t)z * T_TOK * NEXP + li];
    float mx = l;
    for (int s = 32; s; s >>= 1) mx = fmaxf(mx, __shfl_xor(mx, s));
    float e = __expf(l - mx);
    float sum = e;
    for (int s = 32; s; s >>= 1) sum += __shfl_xor(sum, s);
    float prob = e / sum;
    probs_out[li] = prob;
    float v = prob; int idx = lane;
    for (int s = 32; s; s >>= 1) {
        float ov = __shfl_xor(v, s); int oi = __shfl_xor(idx, s);
        if (ov > v || (ov == v && oi < idx)) { v = ov; idx = oi; }
    }
    float v1 = v; int i1 = idx;
    v = (lane == i1) ? -1e30f : prob; idx = lane;
    for (int s = 32; s; s >>= 1) {
        float ov = __shfl_xor(v, s); int oi = __shfl_xor(idx, s);
        if (ov > v || (ov == v && oi < idx)) { v = ov; idx = oi; }
    }
    float v2 = v; int i2 = idx;
    float denom = v1 + v2 + 1e-9f;
    if (lane == 0) {
        int s1 = atomicAdd(&counts[i1], 1);
        if (s1 < CAP) { tok_slot[i1 * CAP + s1] = t; w_slot[i1 * CAP + s1] = v1 / denom; }
        int s2 = atomicAdd(&counts[i2], 1);
        if (s2 < CAP) { tok_slot[i2 * CAP + s2] = t; w_slot[i2 * CAP + s2] = v2 / denom; }
    }
    float g = 0.f;
    const float* xr = X + (size_t)t * DDIM + lane * 16;
    const float* sr = SEG + lane * 16;
#pragma unroll
    for (int j = 0; j < 4; ++j) {
        f32x4 xv = *(const f32x4*)(xr + j * 4);
        f32x4 sv = *(const f32x4*)(sr + j * 4);
#pragma unroll
        for (int q = 0; q < 4; ++q) g += xv[q] * sv[q];
    }
    for (int s = 32; s; s >>= 1) g += __shfl_xor(g, s);
    if (lane == 0) gate_sh[t] = 1.f / (1.f + __expf(-g));
}

// ---------------- gather X -> xg (bf16, per expert slot) and X -> xsh (bf16)
__global__ __launch_bounds__(256) void xgather(const float* __restrict__ X,
                                               const int* __restrict__ counts,
                                               const int* __restrict__ tok_slot,
                                               short* __restrict__ xg,
                                               short* __restrict__ xsh) {
    int b = blockIdx.x, tid = threadIdx.x;
    if (b < 512) {
        int r = b & 7, j = b >> 3;
        int e = (j & 7) * 8 + r;                // e%8 == b%8 -> writer XCD matches gateup reader
        int s0 = (j >> 3) * 32;
        int M = counts[e]; if (M > CAP) M = CAP;
        for (int i = tid; i < 32 * 128; i += 256) {
            int sl = s0 + (i >> 7);
            int ch = i & 127;
            int src = (sl < M) ? tok_slot[e * CAP + sl] : 0;
            const float* p = X + (size_t)src * DDIM + ch * 8;
            f32x4 lo = *(const f32x4*)p, hi = *(const f32x4*)(p + 4);
            *(bf16x8*)(xg + ((size_t)e * CAP + sl) * DDIM + ch * 8) = cvt8(lo, hi);
        }
    } else {
        int r0 = (b - 512) * 32;
        for (int i = tid; i < 32 * 128; i += 256) {
            int row = r0 + (i >> 7), ch = i & 127;
            const float* p = X + (size_t)row * DDIM + ch * 8;
            f32x4 lo = *(const f32x4*)p, hi = *(const f32x4*)(p + 4);
            *(bf16x8*)(xsh + (size_t)row * DDIM + ch * 8) = cvt8(lo, hi);
        }
    }
}

// ---------------- fused gate/up GEMM + SwiGLU -> act (bf16)
// BM=256 (one m-block per expert: weights read ONCE), BN=64 (g and u), BK=32.
// 8 waves (4m x 2n), wave tile 64x32. A bf16 (fragbf), B fp32 (frag32, cvt at read).
// Grid 640: f<512 expert (e%8==f%8 XCD-pinned), f>=512 shared (16 m x 8 n).
// LDS/stage: A 16K + Bg 8K + Bu 8K = 32K; x2 = 64K -> 2 blocks/CU.
__global__ __launch_bounds__(512, 4) void gateup_all(const short* __restrict__ xg,
                                                     const short* __restrict__ xsh,
                                                     const float* __restrict__ GUP,
                                                     const float* __restrict__ SG,
                                                     const float* __restrict__ SU,
                                                     const int* __restrict__ counts,
                                                     short* __restrict__ act,
                                                     short* __restrict__ act_sh) {
    __shared__ char smem[2 * 32768];
    const int NS = DDIM / 32;          // 32 stages
    int f = blockIdx.x;
    bool expert = f < 512;
    int e = 0, m0, n0, M;
    const float *Wg, *Wu;
    const short* Abase;
    short* act_out;
    size_t out_base, arow0;
    if (expert) {
        e = ((f >> 3) & 7) * 8 + (f & 7);
        n0 = (f >> 6) * 64; m0 = 0;
        M = counts[e]; if (M > CAP) M = CAP;
        if (M <= 0) return;
        Wg = GUP + (size_t)e * (2 * IDIM) * DDIM;
        Wu = Wg + (size_t)IDIM * DDIM;
        Abase = xg; arow0 = (size_t)e * CAP;
        act_out = act; out_base = (size_t)e * CAP * IDIM;
    } else {
        int g = f - 512;
        m0 = (g & 15) * 256; n0 = (g >> 4) * 64;
        M = T_TOK; Wg = SG; Wu = SU;
        Abase = xsh; arow0 = (size_t)m0;
        act_out = act_sh; out_base = 0;
    }
    int tid = threadIdx.x, lane = tid & 63, wv = tid >> 6;
    int wm = wv >> 1, wn = wv & 1;

    // A: bf16, chunks {wv, wv+8} of 16 rows (64-B rows, 4 slots)
    int gslA = (lane & 3) ^ ((lane >> 3) & 3);
    const short* gpA0 = Abase + (arow0 + wv * 16 + (lane >> 2)) * DDIM + gslA * 8;
    const short* gpA1 = gpA0 + (size_t)128 * DDIM;
    // B: fp32, chunk wv of 8 rows (128-B rows, 8 slots)
    int gslB = (lane & 7) ^ ((lane >> 3) & 7);
    const float* gpBg = Wg + (size_t)(n0 + wv * 8 + (lane >> 3)) * DDIM + gslB * 4;
    const float* gpBu = Wu + (size_t)(n0 + wv * 8 + (lane >> 3)) * DDIM + gslB * 4;

    auto issue = [&](int buf, int s) {
        char* base = smem + buf * 32768;
        int k = s * 32;
        gload16(gpA0 + k, base + wv * 1024);
        gload16(gpA1 + k, base + (wv + 8) * 1024);
        gload16(gpBg + k, base + 16384 + wv * 1024);
        gload16(gpBu + k, base + 24576 + wv * 1024);
    };

    int fm = lane & 15, sk = lane >> 4;
    f32x4 accg[4][2] = {}, accu[4][2] = {};
    auto compute = [&](int buf) {
        const char* base = smem + buf * 32768;
        bf16x8 bg[2], bu[2];
#pragma unroll
        for (int nt = 0; nt < 2; ++nt) {
            int row = wn * 32 + nt * 16 + fm;
            bg[nt] = frag32(base + 16384, row, sk);
            bu[nt] = frag32(base + 24576, row, sk);
        }
#pragma unroll
        for (int mt = 0; mt < 4; ++mt) {
            bf16x8 a = fragbf(base, wm * 64 + mt * 16 + fm, sk);
#pragma unroll
            for (int nt = 0; nt < 2; ++nt) {
                accg[mt][nt] = __builtin_amdgcn_mfma_f32_16x16x32_bf16(a, bg[nt], accg[mt][nt], 0, 0, 0);
                accu[mt][nt] = __builtin_amdgcn_mfma_f32_16x16x32_bf16(a, bu[nt], accu[mt][nt], 0, 0, 0);
            }
        }
    };

    issue(0, 0);
#pragma unroll 1
    for (int s = 0; s < NS; s += 2) {
        __syncthreads();                 // buf0 (stage s) landed
        if (s + 1 < NS) issue(1, s + 1);
        compute(0);
        __syncthreads();                 // buf1 landed
        if (s + 2 < NS) issue(0, s + 2);
        compute(1);
    }

    int frow = (lane >> 4) * 4, fcol = lane & 15;
#pragma unroll
    for (int mt = 0; mt < 4; ++mt)
#pragma unroll
        for (int r = 0; r < 4; ++r) {
            int row = m0 + wm * 64 + mt * 16 + frow + r;   // expert m0=0
            if ((expert ? (row) : (row - m0)) < (expert ? M : 256) && row < M) {
#pragma unroll
                for (int nt = 0; nt < 2; ++nt) {
                    float g = accg[mt][nt][r];
                    float u = accu[mt][nt][r];
                    float a = (g / (1.f + __expf(-g))) * u;      // silu(g)*u
                    act_out[out_base + (size_t)row * IDIM + (n0 + wn * 32 + nt * 16 + fcol)] = f2bs(a);
                }
            }
        }
}

// ---------------- fused down GEMM (A bf16, W fp32), atomicAdd into zeroed out
// BM=256 (weights once per expert), BN=128, K=512. 8 waves (4m x 2n), wave tile 64x64.
// Grid 640: f<512 expert, f>=512 shared. LDS/stage: A 16K + B 16K = 32K; x2 = 64K.
__global__ __launch_bounds__(512, 4) void down_all(const short* __restrict__ act,
                                                   const short* __restrict__ act_sh,
                                                   const float* __restrict__ DW,
                                                   const float* __restrict__ SD,
                                                   const int* __restrict__ counts,
                                                   const int* __restrict__ tok_slot,
                                                   const float* __restrict__ w_slot,
                                                   const float* __restrict__ gate_sh,
                                                   float* __restrict__ out) {
    __shared__ char smem[2 * 32768];
    const int KD = IDIM;               // 512 both paths
    const int NS = KD / 32;            // 16 stages
    int f = blockIdx.x;
    bool expert = f < 512;
    int e = 0, m0, n0, M;
    const short* A;
    const float* W;
    if (expert) {
        e = ((f >> 3) & 7) * 8 + (f & 7);
        n0 = (f >> 6) * 128; m0 = 0;
        M = counts[e]; if (M > CAP) M = CAP;
        if (M <= 0) return;
        A = act + (size_t)e * CAP * IDIM;
        W = DW + (size_t)e * DDIM * IDIM;
    } else {
        int g = f - 512;
        m0 = (g & 15) * 256; n0 = (g >> 4) * 128;
        M = T_TOK; A = act_sh; W = SD;
    }
    int tid = threadIdx.x, lane = tid & 63, wv = tid >> 6;
    int wm = wv >> 1, wn = wv & 1;

    // A: bf16, chunks {wv, wv+8} of 16 rows
    int gslA = (lane & 3) ^ ((lane >> 3) & 3);
    const short* gpA0 = A + (size_t)(m0 + wv * 16 + (lane >> 2)) * KD + gslA * 8;
    const short* gpA1 = gpA0 + (size_t)128 * KD;
    // B: fp32, chunks {wv, wv+8} of 8 rows
    int gslB = (lane & 7) ^ ((lane >> 3) & 7);
    const float* gpB0 = W + (size_t)(n0 + wv * 8 + (lane >> 3)) * KD + gslB * 4;
    const float* gpB1 = gpB0 + (size_t)64 * KD;

    auto issue = [&](int buf, int s) {
        char* base = smem + buf * 32768;
        int k = s * 32;
        gload16(gpA0 + k, base + wv * 1024);
        gload16(gpA1 + k, base + (wv + 8) * 1024);
        gload16(gpB0 + k, base + 16384 + wv * 1024);
        gload16(gpB1 + k, base + 16384 + (wv + 8) * 1024);
    };

    int fm = lane & 15, sk = lane >> 4;
    f32x4 acc[4][4] = {};
    auto compute = [&](int buf) {
        const char* base = smem + buf * 32768;
        bf16x8 b[4];
#pragma unroll
        for (int nt = 0; nt < 4; ++nt)
            b[nt] = frag32(base + 16384, wn * 64 + nt * 16 + fm, sk);
#pragma unroll
        for (int mt = 0; mt < 4; ++mt) {
            bf16x8 a = fragbf(base, wm * 64 + mt * 16 + fm, sk);
#pragma unroll
            for (int nt = 0; nt < 4; ++nt)
                acc[mt][nt] = __builtin_amdgcn_mfma_f32_16x16x32_bf16(a, b[nt], acc[mt][nt], 0, 0, 0);
        }
    };

    issue(0, 0);
#pragma unroll 1
    for (int s = 0; s < NS; s += 2) {
        __syncthreads();
        if (s + 1 < NS) issue(1, s + 1);
        compute(0);
        __syncthreads();
        if (s + 2 < NS) issue(0, s + 2);
        compute(1);
    }

    int frow = (lane >> 4) * 4, fcol = lane & 15;
#pragma unroll
    for (int mt = 0; mt < 4; ++mt)
#pragma unroll
        for (int r = 0; r < 4; ++r) {
            int lrow = wm * 64 + mt * 16 + frow + r;
            int row = m0 + lrow;                 // expert m0=0
            if (row >= M) continue;
            float scale; int trow;
            if (expert) { scale = w_slot[e * CAP + lrow]; trow = tok_slot[e * CAP + lrow]; }
            else        { scale = gate_sh[row];           trow = row; }
#pragma unroll
            for (int nt = 0; nt < 4; ++nt) {
                int col = n0 + wn * 64 + nt * 16 + fcol;
                atomicAdd(&out[(size_t)trow * DDIM + col], acc[mt][nt][r] * scale);
            }
        }
}

extern "C" void kernel_launch(void* const* d_in, const int* in_sizes, int n_in,
                              void* d_out, int out_size, void* d_ws, size_t ws_size,
                              hipStream_t stream) {
    const float* X   = (const float*)d_in[0];   // hidden_states  [T, D] fp32
    const float* RW  = (const float*)d_in[1];   // router_w       [E, D]
    const float* GUP = (const float*)d_in[2];   // gate_up_proj   [E, 2I, D]
    const float* DW  = (const float*)d_in[3];   // down_proj      [E, D, I]
    const float* SG  = (const float*)d_in[4];   // sh_gate_w      [SI, D]
    const float* SU  = (const float*)d_in[5];   // sh_up_w        [SI, D]
    const float* SD  = (const float*)d_in[6];   // sh_down_w      [D, SI]
    const float* SEG = (const float*)d_in[7];   // sh_expert_gate_w [1, D]
    float* out = (float*)d_out;                 // [T*D] out, then [T*E] probs (fp32)

    char* ws = (char*)d_ws;
    size_t off = 0;
    float* lpart    = (float*)(ws + off); off += (size_t)KZ * T_TOK * NEXP * 4;  // 8 MB
    int*   counts   = (int*)  (ws + off); off += 1024;
    int*   tok_slot = (int*)  (ws + off); off += (size_t)NEXP * CAP * 4;        // 64 KB
    float* w_slot   = (float*)(ws + off); off += (size_t)NEXP * CAP * 4;        // 64 KB
    float* gate_sh  = (float*)(ws + off); off += (size_t)T_TOK * 4;             // 16 KB
    short* act      = (short*)(ws + off); off += (size_t)NEXP * CAP * IDIM * 2; // 16 MB
    short* act_sh   = (short*)(ws + off); off += (size_t)T_TOK * SIDIM * 2;     // 4 MB
    short* xg       = (short*)(ws + off); off += (size_t)NEXP * CAP * DDIM * 2; // 32 MB
    short* xsh      = (short*)(ws + off); off += (size_t)T_TOK * DDIM * 2;      // 8 MB
    (void)ws_size; (void)in_sizes; (void)n_in; (void)out_size;

    hipMemsetAsync(counts, 0, NEXP * sizeof(int), stream);
    hipMemsetAsync(out, 0, (size_t)T_TOK * DDIM * sizeof(float), stream);  // down_all atomicAdds

    logits_kernel<<<dim3(T_TOK / 64, KZ), 256, 0, stream>>>(X, RW, lpart);
    topk_kernel<<<T_TOK / 4, 256, 0, stream>>>(lpart, X, SEG,
                                               out + (size_t)T_TOK * DDIM,
                                               counts, tok_slot, w_slot, gate_sh);
    xgather<<<640, 256, 0, stream>>>(X, counts, tok_slot, xg, xsh);
    gateup_all<<<640, 512, 0, stream>>>(xg, xsh, GUP, SG, SU, counts, act, act_sh);
    down_all<<<640, 512, 0, stream>>>(act, act_sh, DW, SD, counts, tok_slot,
                                      w_slot, gate_sh, out);
}